// Round 15
// baseline (774.768 us; speedup 1.0000x reference)
//
#include <hip/hip_runtime.h>
#include <hip/hip_fp16.h>

#define NN 100000
#define NE 3200000
#define NB 1563            // ceil(NN/64) buckets of 64 receiver nodes
#define NBLK ((NN + 255) / 256)
#define CHUNK 8192
#define NCH 391            // ceil(NE/CHUNK)
#define CAP 4096           // max edges per 64-node bucket (mean 2048, sigma ~45)
#define NKEY 8192          // bsort bins: rl(6b) x sender-granule-1024 (7b)

typedef float f32x4 __attribute__((ext_vector_type(4)));
typedef unsigned int u32x4 __attribute__((ext_vector_type(4)));
typedef unsigned int u32x2 __attribute__((ext_vector_type(2)));

__device__ __forceinline__ float2 h2f2(unsigned int u) {
  __half2 h;
  *reinterpret_cast<unsigned int*>(&h) = u;
  return __half22float2(h);
}
__device__ __forceinline__ unsigned int f2h2(float x, float y) {
  __half2 h = __floats2half2_rn(x, y);
  return *reinterpret_cast<unsigned int*>(&h);
}

// ---------------- pass 1: per-chunk bucket histogram, layout histmat[c*NB + b] ----------------

__global__ __launch_bounds__(1024) void k_hist(const int* __restrict__ recv, int* __restrict__ histmat) {
  __shared__ int h[NB];
  int t = threadIdx.x, c = blockIdx.x;
  for (int i = t; i < NB; i += 1024) h[i] = 0;
  __syncthreads();
  int start = c * CHUNK;
  int end = min(start + CHUNK, NE);
  for (int i = start + t; i < end; i += 1024)
    atomicAdd(&h[__builtin_nontemporal_load(recv + i) >> 6], 1);
  __syncthreads();
  for (int i = t; i < NB; i += 1024) histmat[c * NB + i] = h[i];
}

// ---------------- scan A: per-bucket totals (coalesced over b) ----------------

__global__ __launch_bounds__(256) void k_scanA(const int* __restrict__ histmat, int* __restrict__ total) {
  int b = blockIdx.x * 256 + threadIdx.x;
  if (b >= NB) return;
  int s = 0;
#pragma unroll 4
  for (int c = 0; c < NCH; c++) s += histmat[c * NB + b];
  total[b] = s;
}

// ---------------- scan B: exclusive scan of bucket totals -> boff[b] ----------------

__global__ __launch_bounds__(256) void k_scanB(const int* __restrict__ total, int* __restrict__ boff) {
  __shared__ int ps[256];
  int t = threadIdx.x;
  const int PER = (NB + 255) / 256;  // 7
  int v[PER];
  int s = 0;
#pragma unroll
  for (int k = 0; k < PER; k++) {
    int i = t * PER + k;
    v[k] = (i < NB) ? total[i] : 0;
    s += v[k];
  }
  ps[t] = s;
  __syncthreads();
  for (int o = 1; o < 256; o <<= 1) {
    int x = (t >= o) ? ps[t - o] : 0;
    __syncthreads();
    ps[t] += x;
    __syncthreads();
  }
  int run = (t > 0) ? ps[t - 1] : 0;
#pragma unroll
  for (int k = 0; k < PER; k++) {
    int i = t * PER + k;
    if (i < NB) {
      boff[i] = run;
      run += v[k];
    }
  }
  if (t == 255) boff[NB] = ps[255];
}

// ---------------- scan C: per-bucket running offsets over chunks (coalesced over b) ----------------

__global__ __launch_bounds__(256) void k_scanC(int* __restrict__ histmat, const int* __restrict__ boff) {
  int b = blockIdx.x * 256 + threadIdx.x;
  if (b >= NB) return;
  int run = boff[b];
#pragma unroll 4
  for (int c = 0; c < NCH; c++) {
    int v = histmat[c * NB + b];
    histmat[c * NB + b] = run;
    run += v;
  }
}

// ---------------- pass 2: scatter; coalesced reads AND writes via full LDS record staging ----------

__global__ __launch_bounds__(1024) void k_scat(const int* __restrict__ send, const int* __restrict__ recv,
                                               const float2* __restrict__ ef, const float* __restrict__ mask,
                                               const int* __restrict__ boffc, float4* __restrict__ sorted) {
  __shared__ float4 stg[CHUNK];            // 128 KB
  __shared__ unsigned short bkt[CHUNK];    // 16 KB
  __shared__ int ofs[NB];                  // 6.25 KB
  __shared__ int cur[NB];                  // 6.25 KB
  __shared__ int wsum[16];
  int t = threadIdx.x, c = blockIdx.x;
  int start = c * CHUNK;
  int end = min(start + CHUNK, NE);
  int len = end - start;
  for (int i = t; i < NB; i += 1024) cur[i] = 0;
  __syncthreads();
  for (int i = start + t; i < end; i += 1024)
    atomicAdd(&cur[__builtin_nontemporal_load(recv + i) >> 6], 1);
  __syncthreads();
  int v0 = (2 * t < NB) ? cur[2 * t] : 0;
  int v1 = (2 * t + 1 < NB) ? cur[2 * t + 1] : 0;
  int s = v0 + v1;
  int lane = t & 63, wid = t >> 6;
  for (int o = 1; o < 64; o <<= 1) {
    int x = __shfl_up(s, o);
    if (lane >= o) s += x;
  }
  if (lane == 63) wsum[wid] = s;
  __syncthreads();
  if (wid == 0) {
    int ws = (lane < 16) ? wsum[lane] : 0;
    for (int o = 1; o < 16; o <<= 1) {
      int x = __shfl_up(ws, o);
      if (lane >= o) ws += x;
    }
    if (lane < 16) wsum[lane] = ws;
  }
  __syncthreads();
  int excl = s - v0 - v1 + ((wid > 0) ? wsum[wid - 1] : 0);
  __syncthreads();
  if (2 * t < NB) {
    cur[2 * t] = excl;
    ofs[2 * t] = boffc[c * NB + 2 * t] - excl;
  }
  if (2 * t + 1 < NB) {
    cur[2 * t + 1] = excl + v0;
    ofs[2 * t + 1] = boffc[c * NB + 2 * t + 1] - (excl + v0);
  }
  __syncthreads();
  for (int i = start + t; i < end; i += 1024) {
    int r = recv[i];
    int b = r >> 6;
    int p = atomicAdd(&cur[b], 1);
    float2 e2 = ef[i];
    float4 vv;
    vv.x = __int_as_float((send[i] << 6) | (r & 63));  // 17b sender | 6b local receiver
    vv.y = e2.x;
    vv.z = e2.y;
    vv.w = mask[i];
    stg[p] = vv;
    bkt[p] = (unsigned short)b;
  }
  __syncthreads();
  for (int p = t; p < len; p += 1024) {
    int b = bkt[p];
    sorted[ofs[b] + p] = stg[p];
  }
}

// ---------------- per-bucket counting sort by key=(rl, sender>>10) + row_off ----------------

__global__ __launch_bounds__(256) void k_bsort(const int* __restrict__ boff, float4* __restrict__ sorted,
                                               int* __restrict__ row_off) {
  __shared__ int cnt[NKEY];   // 32 KB
  __shared__ int part[256];
  __shared__ float4 stg[CAP]; // 64 KB
  int t = threadIdx.x, b = blockIdx.x;
  int base = boff[b], end = boff[b + 1];
  int Eb = end - base;
  int n0 = b * 64;
  for (int i = t; i < NKEY; i += 256) cnt[i] = 0;
  __syncthreads();
  for (int e = base + t; e < end; e += 256) {
    int pk = __float_as_int(sorted[e].x);
    int key = ((pk & 63) << 7) | (pk >> 16);  // rl major, 1024-node sender granule minor
    atomicAdd(&cnt[key], 1);
  }
  __syncthreads();
  int s = 0;
#pragma unroll
  for (int k = 0; k < 32; k++) s += cnt[t * 32 + k];
  part[t] = s;
  __syncthreads();
  for (int o = 1; o < 256; o <<= 1) {
    int x = (t >= o) ? part[t - o] : 0;
    __syncthreads();
    part[t] += x;
    __syncthreads();
  }
  int run = part[t] - s;
#pragma unroll
  for (int k = 0; k < 32; k++) {
    int c = cnt[t * 32 + k];
    cnt[t * 32 + k] = run;
    run += c;
  }
  __syncthreads();
  if (t < 64) {
    int n = n0 + t;
    if (n < NN) row_off[n] = base + cnt[t << 7];
  }
  if (b == NB - 1 && t == 0) row_off[NN] = end;
  __syncthreads();
  for (int e = base + t; e < end; e += 256) {
    float4 r = sorted[e];
    int pk = __float_as_int(r.x);
    int key = ((pk & 63) << 7) | (pk >> 16);
    int p = atomicAdd(&cnt[key], 1);
    stg[p] = r;
  }
  __syncthreads();
  for (int i = t; i < Eb; i += 256) sorted[base + i] = stg[i];
}

// ---------------- init: h = PQ@W_in + b_in ; Vp=(1,0); layer-0 a,b projections ----------------
// a stored fp16 GROUP-major: a[(g*NN + n)*16 + c] for channel g*16+c -> 32B line per node-group.

__global__ __launch_bounds__(256) void k_init(const float2* __restrict__ PQ,
                                              const float* __restrict__ Win, const float* __restrict__ bin,
                                              const float* __restrict__ Wm, const float* __restrict__ bm,
                                              float* __restrict__ h, __half* __restrict__ a,
                                              float* __restrict__ bp, float2* __restrict__ Vp) {
  int n = blockIdx.x * 256 + threadIdx.x;
  if (n >= NN) return;
  float2 pq = PQ[n];
  float hh[32];
#pragma unroll
  for (int j = 0; j < 32; j++) hh[j] = fmaf(pq.x, Win[j], fmaf(pq.y, Win[32 + j], bin[j]));
  float4* h4 = (float4*)(h + (size_t)n * 32);
#pragma unroll
  for (int j = 0; j < 8; j++) h4[j] = make_float4(hh[4*j], hh[4*j+1], hh[4*j+2], hh[4*j+3]);
  Vp[n] = make_float2(1.0f, 0.0f);
  float av[32], bv[32];
#pragma unroll
  for (int j = 0; j < 32; j++) { av[j] = Wm[j]; bv[j] = Wm[34 * 32 + j] + bm[j]; }
#pragma unroll 1
  for (int k = 0; k < 32; k++) {
    float hk = hh[k];
#pragma unroll
    for (int j = 0; j < 32; j++) {
      av[j] = fmaf(hk, Wm[(2 + k) * 32 + j], av[j]);
      bv[j] = fmaf(hk, Wm[(36 + k) * 32 + j], bv[j]);
    }
  }
#pragma unroll
  for (int g = 0; g < 2; g++) {
    u32x4 p0, p1;
    p0.x = f2h2(av[g*16+0],  av[g*16+1]);  p0.y = f2h2(av[g*16+2],  av[g*16+3]);
    p0.z = f2h2(av[g*16+4],  av[g*16+5]);  p0.w = f2h2(av[g*16+6],  av[g*16+7]);
    p1.x = f2h2(av[g*16+8],  av[g*16+9]);  p1.y = f2h2(av[g*16+10], av[g*16+11]);
    p1.z = f2h2(av[g*16+12], av[g*16+13]); p1.w = f2h2(av[g*16+14], av[g*16+15]);
    u32x4* dst = (u32x4*)(a + ((size_t)g * NN + n) * 16);
    dst[0] = p0;
    dst[1] = p1;
  }
  float4* b4 = (float4*)(bp + (size_t)n * 32);
#pragma unroll
  for (int j = 0; j < 8; j++) b4[j] = make_float4(bv[4*j], bv[4*j+1], bv[4*j+2], bv[4*j+3]);
}

// ---------------- per-layer edge aggregation: one channel-group per dispatch ----------------
// During dispatch g every CU gathers only slice g (3.2MB) -> fits each XCD's 4MB L2 -> L2 hits.
// 4 lanes/node, 4 ch/lane (8B gather); 2-deep gather pipeline; sender-sweep order.

__global__ __launch_bounds__(256) void k_edge(const __half* __restrict__ a, const float* __restrict__ bp,
                                              const int* __restrict__ row_off, const f32x4* __restrict__ sorted,
                                              const float* __restrict__ Wm, float* __restrict__ agg, int g) {
  int t = threadIdx.x;
  int n = blockIdx.x * 64 + (t >> 2);
  if (n >= NN) return;
  int cl = (t & 3) * 4;           // channel within group
  int ch = g * 16 + cl;           // global channel
  const float* wr = Wm + 68 * 32 + ch;
  float w0[4], w1[4];
#pragma unroll
  for (int j = 0; j < 4; j++) { w0[j] = wr[j]; w1[j] = wr[32 + j]; }
  const float4 bnv = *(const float4*)(bp + (size_t)n * 32 + ch);
  float bn[4] = {bnv.x, bnv.y, bnv.z, bnv.w};
  float acc[4] = {0.f, 0.f, 0.f, 0.f};
  const __half* abase = a + (size_t)g * NN * 16 + cl;
  int e0 = row_off[n], e1 = row_off[n + 1];
  f32x4 r0 = {0,0,0,0}, r1 = {0,0,0,0}, r2 = {0,0,0,0};
  u32x2 gA = {0, 0}, gB = {0, 0};
  if (e0 < e1)     r0 = __builtin_nontemporal_load(sorted + e0);
  if (e0 + 1 < e1) r1 = __builtin_nontemporal_load(sorted + e0 + 1);
  if (e0 + 2 < e1) r2 = __builtin_nontemporal_load(sorted + e0 + 2);
  if (e0 < e1)     gA = *(const u32x2*)(abase + (size_t)(__float_as_int(r0.x) >> 6) * 16);
  if (e0 + 1 < e1) gB = *(const u32x2*)(abase + (size_t)(__float_as_int(r1.x) >> 6) * 16);
  for (int e = e0; e < e1; ++e) {
    f32x4 rc = r0;
    u32x2 q = gA;
    r0 = r1; r1 = r2; gA = gB;
    if (e + 3 < e1) r2 = __builtin_nontemporal_load(sorted + e + 3);   // record 3 ahead
    if (e + 2 < e1)                                                    // gather 2 ahead
      gB = *(const u32x2*)(abase + (size_t)(__float_as_int(r1.x) >> 6) * 16);
    float c0 = rc.y, c1 = rc.z, mk = rc.w;
    float2 f0 = h2f2(q.x), f1 = h2f2(q.y);
    float av[4] = {f0.x, f0.y, f1.x, f1.y};
#pragma unroll
    for (int j = 0; j < 4; j++)
      acc[j] = fmaf(fmaxf(av[j] + fmaf(c0, w0[j], fmaf(c1, w1[j], bn[j])), 0.f), mk, acc[j]);
  }
  *(float4*)(agg + (size_t)n * 32 + ch) = make_float4(acc[0], acc[1], acc[2], acc[3]);
}

// ---------------- per-layer node update (+ next-layer projections fused) ----------------

__global__ __launch_bounds__(256) void k_node(const float* __restrict__ agg,
                                              const float* __restrict__ Wu, const float* __restrict__ bu,
                                              const float* __restrict__ Wd, const float* __restrict__ bd,
                                              const float* __restrict__ Wm, const float* __restrict__ bm,
                                              float* __restrict__ h, __half* __restrict__ a,
                                              float* __restrict__ bp, float2* __restrict__ Vp,
                                              float2* __restrict__ out, int last) {
  int n = blockIdx.x * 256 + threadIdx.x;
  if (n >= NN) return;
  float2 vp = Vp[n];
  float v0 = vp.x, v1 = vp.y;
  float hh[32], ag[32];
  const float4* h4 = (const float4*)(h + (size_t)n * 32);
  const float4* g4 = (const float4*)(agg + (size_t)n * 32);
#pragma unroll
  for (int jj = 0; jj < 8; jj++) {
    float4 x = h4[jj];
    hh[4*jj] = x.x; hh[4*jj+1] = x.y; hh[4*jj+2] = x.z; hh[4*jj+3] = x.w;
    float4 y = g4[jj];
    ag[4*jj] = y.x; ag[4*jj+1] = y.y; ag[4*jj+2] = y.z; ag[4*jj+3] = y.w;
  }
  float vo[32];
#pragma unroll
  for (int j = 0; j < 32; j++) vo[j] = fmaf(v0, Wu[j], fmaf(v1, Wu[32 + j], bu[j]));
#pragma unroll 1
  for (int k = 0; k < 32; k++) {
    float hk = hh[k], ak = ag[k];
#pragma unroll
    for (int j = 0; j < 32; j++) {
      vo[j] = fmaf(hk, Wu[(2 + k) * 32 + j], vo[j]);
      vo[j] = fmaf(ak, Wu[(34 + k) * 32 + j], vo[j]);
    }
  }
#pragma unroll
  for (int j = 0; j < 32; j++) hh[j] = fmaxf(vo[j], 0.0f);
  float d0 = bd[0], d1 = bd[1];
#pragma unroll 1
  for (int k = 0; k < 32; k++) {
    d0 = fmaf(hh[k], Wd[2 * k], d0);
    d1 = fmaf(hh[k], Wd[2 * k + 1], d1);
  }
  v0 += d0;
  v1 += d1;
  if (last) {
    out[n] = make_float2(v0, v1);
    return;
  }
  Vp[n] = make_float2(v0, v1);
  float4* hw4 = (float4*)(h + (size_t)n * 32);
#pragma unroll
  for (int jj = 0; jj < 8; jj++) hw4[jj] = make_float4(hh[4*jj], hh[4*jj+1], hh[4*jj+2], hh[4*jj+3]);
  float av[32], bv[32];
#pragma unroll
  for (int j = 0; j < 32; j++) {
    av[j] = fmaf(v0, Wm[j], v1 * Wm[32 + j]);
    bv[j] = fmaf(v0, Wm[34 * 32 + j], fmaf(v1, Wm[35 * 32 + j], bm[j]));
  }
#pragma unroll 1
  for (int k = 0; k < 32; k++) {
    float hk = hh[k];
#pragma unroll
    for (int j = 0; j < 32; j++) {
      av[j] = fmaf(hk, Wm[(2 + k) * 32 + j], av[j]);
      bv[j] = fmaf(hk, Wm[(36 + k) * 32 + j], bv[j]);
    }
  }
#pragma unroll
  for (int g = 0; g < 2; g++) {
    u32x4 p0, p1;
    p0.x = f2h2(av[g*16+0],  av[g*16+1]);  p0.y = f2h2(av[g*16+2],  av[g*16+3]);
    p0.z = f2h2(av[g*16+4],  av[g*16+5]);  p0.w = f2h2(av[g*16+6],  av[g*16+7]);
    p1.x = f2h2(av[g*16+8],  av[g*16+9]);  p1.y = f2h2(av[g*16+10], av[g*16+11]);
    p1.z = f2h2(av[g*16+12], av[g*16+13]); p1.w = f2h2(av[g*16+14], av[g*16+15]);
    u32x4* dst = (u32x4*)(a + ((size_t)g * NN + n) * 16);
    dst[0] = p0;
    dst[1] = p1;
  }
  float4* b4 = (float4*)(bp + (size_t)n * 32);
#pragma unroll
  for (int jj = 0; jj < 8; jj++) b4[jj] = make_float4(bv[4*jj], bv[4*jj+1], bv[4*jj+2], bv[4*jj+3]);
}

// ---------------- launch ----------------

extern "C" void kernel_launch(void* const* d_in, const int* in_sizes, int n_in,
                              void* d_out, int out_size, void* d_ws, size_t ws_size,
                              hipStream_t stream) {
  const float* PQ   = (const float*)d_in[0];
  const int*   send = (const int*)d_in[1];
  const int*   recv = (const int*)d_in[2];
  const float* ef   = (const float*)d_in[3];
  const float* mask = (const float*)d_in[4];
  const float* Win  = (const float*)d_in[5];
  const float* bin  = (const float*)d_in[6];
  const float* Wmsg = (const float*)d_in[7];   // [3,70,32]
  const float* bmsg = (const float*)d_in[8];   // [3,32]
  const float* Wupd = (const float*)d_in[9];   // [3,66,32]
  const float* bupd = (const float*)d_in[10];  // [3,32]
  const float* Wdel = (const float*)d_in[11];  // [3,32,2]
  const float* bdel = (const float*)d_in[12];  // [3,2]
  float2* out = (float2*)d_out;

  char* w = (char*)d_ws;
  auto alloc = [&](size_t bytes) {
    char* p = w;
    w += (bytes + 255) & ~(size_t)255;
    return p;
  };
  float4* sorted = (float4*)alloc((size_t)NE * 16);
  int* histmat = (int*)alloc((size_t)NCH * NB * 4);  // [c][b]; in-place -> per-chunk offsets
  int* total   = (int*)alloc((size_t)NB * 4);
  int* boff    = (int*)alloc(((size_t)NB + 1) * 4);
  int* row_off = (int*)alloc(((size_t)NN + 1) * 4);
  float* h    = (float*)alloc((size_t)NN * 32 * 4);
  __half* a   = (__half*)alloc((size_t)NN * 32 * 2);
  float* bp   = (float*)alloc((size_t)NN * 32 * 4);
  float* agg  = (float*)alloc((size_t)NN * 32 * 4);
  float2* Vp  = (float2*)alloc((size_t)NN * 8);

  k_hist<<<NCH, 1024, 0, stream>>>(recv, histmat);
  k_scanA<<<(NB + 255) / 256, 256, 0, stream>>>(histmat, total);
  k_scanB<<<1, 256, 0, stream>>>(total, boff);
  k_scanC<<<(NB + 255) / 256, 256, 0, stream>>>(histmat, boff);
  k_scat<<<NCH, 1024, 0, stream>>>(send, recv, (const float2*)ef, mask, histmat, sorted);
  k_bsort<<<NB, 256, 0, stream>>>(boff, sorted, row_off);

  k_init<<<NBLK, 256, 0, stream>>>((const float2*)PQ, Win, bin, Wmsg, bmsg, h, a, bp, Vp);

  for (int l = 0; l < 3; l++) {
    int last = (l == 2) ? 1 : 0;
    int lnext = (l + 1) % 3;
    k_edge<<<NB, 256, 0, stream>>>(a, bp, row_off, (const f32x4*)sorted, Wmsg + l * 70 * 32, agg, 0);
    k_edge<<<NB, 256, 0, stream>>>(a, bp, row_off, (const f32x4*)sorted, Wmsg + l * 70 * 32, agg, 1);
    k_node<<<NBLK, 256, 0, stream>>>(agg, Wupd + l * 66 * 32, bupd + l * 32,
                                     Wdel + l * 64, bdel + l * 2,
                                     Wmsg + lnext * 70 * 32, bmsg + lnext * 32,
                                     h, a, bp, Vp, out, last);
  }
}

// Round 16
// 557.717 us; speedup vs baseline: 1.3892x; 1.3892x over previous
//
#include <hip/hip_runtime.h>
#include <hip/hip_fp16.h>

#define NN 100000
#define NE 3200000
#define NB 1563            // ceil(NN/64) buckets of 64 receiver nodes
#define NBLK ((NN + 255) / 256)
#define CHUNK 8192
#define NCH 391            // ceil(NE/CHUNK)
#define CAP 4096           // max edges per 64-node bucket (mean 2048, sigma ~45)
#define NKEY 8192          // bsort bins: rl(6b) x sender-granule-1024 (7b)
#define EBK2 ((NN + 31) / 32)   // k_edge: 32 nodes/block, 128 threads

typedef float f32x4 __attribute__((ext_vector_type(4)));
typedef unsigned int u32x4 __attribute__((ext_vector_type(4)));

__device__ __forceinline__ float2 h2f2(unsigned int u) {
  __half2 h;
  *reinterpret_cast<unsigned int*>(&h) = u;
  return __half22float2(h);
}
__device__ __forceinline__ unsigned int f2h2(float x, float y) {
  __half2 h = __floats2half2_rn(x, y);
  return *reinterpret_cast<unsigned int*>(&h);
}

// ---------------- pass 1: per-chunk bucket histogram, layout histmat[c*NB + b] ----------------

__global__ __launch_bounds__(1024) void k_hist(const int* __restrict__ recv, int* __restrict__ histmat) {
  __shared__ int h[NB];
  int t = threadIdx.x, c = blockIdx.x;
  for (int i = t; i < NB; i += 1024) h[i] = 0;
  __syncthreads();
  int start = c * CHUNK;
  int end = min(start + CHUNK, NE);
  for (int i = start + t; i < end; i += 1024)
    atomicAdd(&h[__builtin_nontemporal_load(recv + i) >> 6], 1);
  __syncthreads();
  for (int i = t; i < NB; i += 1024) histmat[c * NB + i] = h[i];
}

// ---------------- scan A: per-bucket totals (coalesced over b) ----------------

__global__ __launch_bounds__(256) void k_scanA(const int* __restrict__ histmat, int* __restrict__ total) {
  int b = blockIdx.x * 256 + threadIdx.x;
  if (b >= NB) return;
  int s = 0;
#pragma unroll 4
  for (int c = 0; c < NCH; c++) s += histmat[c * NB + b];
  total[b] = s;
}

// ---------------- scan B: exclusive scan of bucket totals -> boff[b] ----------------

__global__ __launch_bounds__(256) void k_scanB(const int* __restrict__ total, int* __restrict__ boff) {
  __shared__ int ps[256];
  int t = threadIdx.x;
  const int PER = (NB + 255) / 256;  // 7
  int v[PER];
  int s = 0;
#pragma unroll
  for (int k = 0; k < PER; k++) {
    int i = t * PER + k;
    v[k] = (i < NB) ? total[i] : 0;
    s += v[k];
  }
  ps[t] = s;
  __syncthreads();
  for (int o = 1; o < 256; o <<= 1) {
    int x = (t >= o) ? ps[t - o] : 0;
    __syncthreads();
    ps[t] += x;
    __syncthreads();
  }
  int run = (t > 0) ? ps[t - 1] : 0;
#pragma unroll
  for (int k = 0; k < PER; k++) {
    int i = t * PER + k;
    if (i < NB) {
      boff[i] = run;
      run += v[k];
    }
  }
  if (t == 255) boff[NB] = ps[255];
}

// ---------------- scan C: per-bucket running offsets over chunks (coalesced over b) ----------------

__global__ __launch_bounds__(256) void k_scanC(int* __restrict__ histmat, const int* __restrict__ boff) {
  int b = blockIdx.x * 256 + threadIdx.x;
  if (b >= NB) return;
  int run = boff[b];
#pragma unroll 4
  for (int c = 0; c < NCH; c++) {
    int v = histmat[c * NB + b];
    histmat[c * NB + b] = run;
    run += v;
  }
}

// ---------------- pass 2: scatter; coalesced reads AND writes via full LDS record staging ----------

__global__ __launch_bounds__(1024) void k_scat(const int* __restrict__ send, const int* __restrict__ recv,
                                               const float2* __restrict__ ef, const float* __restrict__ mask,
                                               const int* __restrict__ boffc, float4* __restrict__ sorted) {
  __shared__ float4 stg[CHUNK];            // 128 KB
  __shared__ unsigned short bkt[CHUNK];    // 16 KB
  __shared__ int ofs[NB];                  // 6.25 KB
  __shared__ int cur[NB];                  // 6.25 KB
  __shared__ int wsum[16];
  int t = threadIdx.x, c = blockIdx.x;
  int start = c * CHUNK;
  int end = min(start + CHUNK, NE);
  int len = end - start;
  for (int i = t; i < NB; i += 1024) cur[i] = 0;
  __syncthreads();
  for (int i = start + t; i < end; i += 1024)
    atomicAdd(&cur[__builtin_nontemporal_load(recv + i) >> 6], 1);
  __syncthreads();
  int v0 = (2 * t < NB) ? cur[2 * t] : 0;
  int v1 = (2 * t + 1 < NB) ? cur[2 * t + 1] : 0;
  int s = v0 + v1;
  int lane = t & 63, wid = t >> 6;
  for (int o = 1; o < 64; o <<= 1) {
    int x = __shfl_up(s, o);
    if (lane >= o) s += x;
  }
  if (lane == 63) wsum[wid] = s;
  __syncthreads();
  if (wid == 0) {
    int ws = (lane < 16) ? wsum[lane] : 0;
    for (int o = 1; o < 16; o <<= 1) {
      int x = __shfl_up(ws, o);
      if (lane >= o) ws += x;
    }
    if (lane < 16) wsum[lane] = ws;
  }
  __syncthreads();
  int excl = s - v0 - v1 + ((wid > 0) ? wsum[wid - 1] : 0);
  __syncthreads();
  if (2 * t < NB) {
    cur[2 * t] = excl;
    ofs[2 * t] = boffc[c * NB + 2 * t] - excl;
  }
  if (2 * t + 1 < NB) {
    cur[2 * t + 1] = excl + v0;
    ofs[2 * t + 1] = boffc[c * NB + 2 * t + 1] - (excl + v0);
  }
  __syncthreads();
  for (int i = start + t; i < end; i += 1024) {
    int r = recv[i];
    int b = r >> 6;
    int p = atomicAdd(&cur[b], 1);
    float2 e2 = ef[i];
    float4 vv;
    vv.x = __int_as_float((send[i] << 6) | (r & 63));  // 17b sender | 6b local receiver
    vv.y = e2.x;
    vv.z = e2.y;
    vv.w = mask[i];
    stg[p] = vv;
    bkt[p] = (unsigned short)b;
  }
  __syncthreads();
  for (int p = t; p < len; p += 1024) {
    int b = bkt[p];
    sorted[ofs[b] + p] = stg[p];
  }
}

// ---------------- per-bucket counting sort by key=(rl, sender>>10) + row_off ----------------

__global__ __launch_bounds__(256) void k_bsort(const int* __restrict__ boff, float4* __restrict__ sorted,
                                               int* __restrict__ row_off) {
  __shared__ int cnt[NKEY];   // 32 KB
  __shared__ int part[256];
  __shared__ float4 stg[CAP]; // 64 KB
  int t = threadIdx.x, b = blockIdx.x;
  int base = boff[b], end = boff[b + 1];
  int Eb = end - base;
  int n0 = b * 64;
  for (int i = t; i < NKEY; i += 256) cnt[i] = 0;
  __syncthreads();
  for (int e = base + t; e < end; e += 256) {
    int pk = __float_as_int(sorted[e].x);
    int key = ((pk & 63) << 7) | (pk >> 16);  // rl major, 1024-node sender granule minor
    atomicAdd(&cnt[key], 1);
  }
  __syncthreads();
  int s = 0;
#pragma unroll
  for (int k = 0; k < 32; k++) s += cnt[t * 32 + k];
  part[t] = s;
  __syncthreads();
  for (int o = 1; o < 256; o <<= 1) {
    int x = (t >= o) ? part[t - o] : 0;
    __syncthreads();
    part[t] += x;
    __syncthreads();
  }
  int run = part[t] - s;
#pragma unroll
  for (int k = 0; k < 32; k++) {
    int c = cnt[t * 32 + k];
    cnt[t * 32 + k] = run;
    run += c;
  }
  __syncthreads();
  if (t < 64) {
    int n = n0 + t;
    if (n < NN) row_off[n] = base + cnt[t << 7];
  }
  if (b == NB - 1 && t == 0) row_off[NN] = end;
  __syncthreads();
  for (int e = base + t; e < end; e += 256) {
    float4 r = sorted[e];
    int pk = __float_as_int(r.x);
    int key = ((pk & 63) << 7) | (pk >> 16);
    int p = atomicAdd(&cnt[key], 1);
    stg[p] = r;
  }
  __syncthreads();
  for (int i = t; i < Eb; i += 256) sorted[base + i] = stg[i];
}

// ---------------- init: h = PQ@W_in + b_in ; Vp=(1,0); layer-0 a,b projections ----------------
// a stored fp16 node-major: a[n*32 + ch] -> one 64B line per node.

__global__ __launch_bounds__(256) void k_init(const float2* __restrict__ PQ,
                                              const float* __restrict__ Win, const float* __restrict__ bin,
                                              const float* __restrict__ Wm, const float* __restrict__ bm,
                                              float* __restrict__ h, __half* __restrict__ a,
                                              float* __restrict__ bp, float2* __restrict__ Vp) {
  int n = blockIdx.x * 256 + threadIdx.x;
  if (n >= NN) return;
  float2 pq = PQ[n];
  float hh[32];
#pragma unroll
  for (int j = 0; j < 32; j++) hh[j] = fmaf(pq.x, Win[j], fmaf(pq.y, Win[32 + j], bin[j]));
  float4* h4 = (float4*)(h + (size_t)n * 32);
#pragma unroll
  for (int j = 0; j < 8; j++) h4[j] = make_float4(hh[4*j], hh[4*j+1], hh[4*j+2], hh[4*j+3]);
  Vp[n] = make_float2(1.0f, 0.0f);
  float av[32], bv[32];
#pragma unroll
  for (int j = 0; j < 32; j++) { av[j] = Wm[j]; bv[j] = Wm[34 * 32 + j] + bm[j]; }
#pragma unroll 1
  for (int k = 0; k < 32; k++) {
    float hk = hh[k];
#pragma unroll
    for (int j = 0; j < 32; j++) {
      av[j] = fmaf(hk, Wm[(2 + k) * 32 + j], av[j]);
      bv[j] = fmaf(hk, Wm[(36 + k) * 32 + j], bv[j]);
    }
  }
  u32x4* dst = (u32x4*)(a + (size_t)n * 32);
#pragma unroll
  for (int g = 0; g < 4; g++) {
    u32x4 p;
    p.x = f2h2(av[g*8+0], av[g*8+1]);
    p.y = f2h2(av[g*8+2], av[g*8+3]);
    p.z = f2h2(av[g*8+4], av[g*8+5]);
    p.w = f2h2(av[g*8+6], av[g*8+7]);
    dst[g] = p;
  }
  float4* b4 = (float4*)(bp + (size_t)n * 32);
#pragma unroll
  for (int j = 0; j < 8; j++) b4[j] = make_float4(bv[4*j], bv[4*j+1], bv[4*j+2], bv[4*j+3]);
}

// ---------------- per-layer edge aggregation: 4 lanes/node + 2-deep gather pipeline ----------------
// 128-thread blocks (32 nodes) -> 3125 blocks (~12.2/CU) for even packing + small tail.

__global__ __launch_bounds__(128) void k_edge(const __half* __restrict__ a, const float* __restrict__ bp,
                                              const int* __restrict__ row_off, const f32x4* __restrict__ sorted,
                                              const float* __restrict__ Wm, float* __restrict__ agg) {
  int t = threadIdx.x;
  int n = blockIdx.x * 32 + (t >> 2);
  if (n >= NN) return;
  int ch = (t & 3) * 8;
  const float* wr = Wm + 68 * 32 + ch;
  float w0[8], w1[8];
#pragma unroll
  for (int j = 0; j < 8; j++) { w0[j] = wr[j]; w1[j] = wr[32 + j]; }
  const float4 bna = *(const float4*)(bp + (size_t)n * 32 + ch);
  const float4 bnb = *(const float4*)(bp + (size_t)n * 32 + ch + 4);
  float bn[8] = {bna.x, bna.y, bna.z, bna.w, bnb.x, bnb.y, bnb.z, bnb.w};
  float acc[8] = {0.f, 0.f, 0.f, 0.f, 0.f, 0.f, 0.f, 0.f};
  const __half* abase = a + ch;
  int e0 = row_off[n], e1 = row_off[n + 1];
  f32x4 r0 = {0,0,0,0}, r1 = {0,0,0,0}, r2 = {0,0,0,0};
  u32x4 gA = {0,0,0,0}, gB = {0,0,0,0};
  if (e0 < e1)     r0 = __builtin_nontemporal_load(sorted + e0);
  if (e0 + 1 < e1) r1 = __builtin_nontemporal_load(sorted + e0 + 1);
  if (e0 + 2 < e1) r2 = __builtin_nontemporal_load(sorted + e0 + 2);
  if (e0 < e1)     gA = *(const u32x4*)(abase + (size_t)(__float_as_int(r0.x) >> 6) * 32);
  if (e0 + 1 < e1) gB = *(const u32x4*)(abase + (size_t)(__float_as_int(r1.x) >> 6) * 32);
  for (int e = e0; e < e1; ++e) {
    f32x4 rc = r0;
    u32x4 q = gA;
    r0 = r1; r1 = r2; gA = gB;
    if (e + 3 < e1) r2 = __builtin_nontemporal_load(sorted + e + 3);   // record 3 ahead
    if (e + 2 < e1)                                                    // gather 2 ahead (r1 = rec e+2)
      gB = *(const u32x4*)(abase + (size_t)(__float_as_int(r1.x) >> 6) * 32);
    float c0 = rc.y, c1 = rc.z, mk = rc.w;
    float2 f0 = h2f2(q.x), f1 = h2f2(q.y), f2 = h2f2(q.z), f3 = h2f2(q.w);
    float av[8] = {f0.x, f0.y, f1.x, f1.y, f2.x, f2.y, f3.x, f3.y};
#pragma unroll
    for (int j = 0; j < 8; j++)
      acc[j] = fmaf(fmaxf(av[j] + fmaf(c0, w0[j], fmaf(c1, w1[j], bn[j])), 0.f), mk, acc[j]);
  }
  float* gp = agg + (size_t)n * 32 + ch;
  *(float4*)gp       = make_float4(acc[0], acc[1], acc[2], acc[3]);
  *(float4*)(gp + 4) = make_float4(acc[4], acc[5], acc[6], acc[7]);
}

// ---------------- per-layer node update (+ next-layer projections fused) ----------------

__global__ __launch_bounds__(256) void k_node(const float* __restrict__ agg,
                                              const float* __restrict__ Wu, const float* __restrict__ bu,
                                              const float* __restrict__ Wd, const float* __restrict__ bd,
                                              const float* __restrict__ Wm, const float* __restrict__ bm,
                                              float* __restrict__ h, __half* __restrict__ a,
                                              float* __restrict__ bp, float2* __restrict__ Vp,
                                              float2* __restrict__ out, int last) {
  int n = blockIdx.x * 256 + threadIdx.x;
  if (n >= NN) return;
  float2 vp = Vp[n];
  float v0 = vp.x, v1 = vp.y;
  float hh[32], ag[32];
  const float4* h4 = (const float4*)(h + (size_t)n * 32);
  const float4* g4 = (const float4*)(agg + (size_t)n * 32);
#pragma unroll
  for (int jj = 0; jj < 8; jj++) {
    float4 x = h4[jj];
    hh[4*jj] = x.x; hh[4*jj+1] = x.y; hh[4*jj+2] = x.z; hh[4*jj+3] = x.w;
    float4 y = g4[jj];
    ag[4*jj] = y.x; ag[4*jj+1] = y.y; ag[4*jj+2] = y.z; ag[4*jj+3] = y.w;
  }
  float vo[32];
#pragma unroll
  for (int j = 0; j < 32; j++) vo[j] = fmaf(v0, Wu[j], fmaf(v1, Wu[32 + j], bu[j]));
#pragma unroll 1
  for (int k = 0; k < 32; k++) {
    float hk = hh[k], ak = ag[k];
#pragma unroll
    for (int j = 0; j < 32; j++) {
      vo[j] = fmaf(hk, Wu[(2 + k) * 32 + j], vo[j]);
      vo[j] = fmaf(ak, Wu[(34 + k) * 32 + j], vo[j]);
    }
  }
#pragma unroll
  for (int j = 0; j < 32; j++) hh[j] = fmaxf(vo[j], 0.0f);
  float d0 = bd[0], d1 = bd[1];
#pragma unroll 1
  for (int k = 0; k < 32; k++) {
    d0 = fmaf(hh[k], Wd[2 * k], d0);
    d1 = fmaf(hh[k], Wd[2 * k + 1], d1);
  }
  v0 += d0;
  v1 += d1;
  if (last) {
    out[n] = make_float2(v0, v1);
    return;
  }
  Vp[n] = make_float2(v0, v1);
  float4* hw4 = (float4*)(h + (size_t)n * 32);
#pragma unroll
  for (int jj = 0; jj < 8; jj++) hw4[jj] = make_float4(hh[4*jj], hh[4*jj+1], hh[4*jj+2], hh[4*jj+3]);
  float av[32], bv[32];
#pragma unroll
  for (int j = 0; j < 32; j++) {
    av[j] = fmaf(v0, Wm[j], v1 * Wm[32 + j]);
    bv[j] = fmaf(v0, Wm[34 * 32 + j], fmaf(v1, Wm[35 * 32 + j], bm[j]));
  }
#pragma unroll 1
  for (int k = 0; k < 32; k++) {
    float hk = hh[k];
#pragma unroll
    for (int j = 0; j < 32; j++) {
      av[j] = fmaf(hk, Wm[(2 + k) * 32 + j], av[j]);
      bv[j] = fmaf(hk, Wm[(36 + k) * 32 + j], bv[j]);
    }
  }
  u32x4* dst = (u32x4*)(a + (size_t)n * 32);
#pragma unroll
  for (int g = 0; g < 4; g++) {
    u32x4 p;
    p.x = f2h2(av[g*8+0], av[g*8+1]);
    p.y = f2h2(av[g*8+2], av[g*8+3]);
    p.z = f2h2(av[g*8+4], av[g*8+5]);
    p.w = f2h2(av[g*8+6], av[g*8+7]);
    dst[g] = p;
  }
  float4* b4 = (float4*)(bp + (size_t)n * 32);
#pragma unroll
  for (int jj = 0; jj < 8; jj++) b4[jj] = make_float4(bv[4*jj], bv[4*jj+1], bv[4*jj+2], bv[4*jj+3]);
}

// ---------------- launch ----------------

extern "C" void kernel_launch(void* const* d_in, const int* in_sizes, int n_in,
                              void* d_out, int out_size, void* d_ws, size_t ws_size,
                              hipStream_t stream) {
  const float* PQ   = (const float*)d_in[0];
  const int*   send = (const int*)d_in[1];
  const int*   recv = (const int*)d_in[2];
  const float* ef   = (const float*)d_in[3];
  const float* mask = (const float*)d_in[4];
  const float* Win  = (const float*)d_in[5];
  const float* bin  = (const float*)d_in[6];
  const float* Wmsg = (const float*)d_in[7];   // [3,70,32]
  const float* bmsg = (const float*)d_in[8];   // [3,32]
  const float* Wupd = (const float*)d_in[9];   // [3,66,32]
  const float* bupd = (const float*)d_in[10];  // [3,32]
  const float* Wdel = (const float*)d_in[11];  // [3,32,2]
  const float* bdel = (const float*)d_in[12];  // [3,2]
  float2* out = (float2*)d_out;

  char* w = (char*)d_ws;
  auto alloc = [&](size_t bytes) {
    char* p = w;
    w += (bytes + 255) & ~(size_t)255;
    return p;
  };
  float4* sorted = (float4*)alloc((size_t)NE * 16);
  int* histmat = (int*)alloc((size_t)NCH * NB * 4);  // [c][b]; in-place -> per-chunk offsets
  int* total   = (int*)alloc((size_t)NB * 4);
  int* boff    = (int*)alloc(((size_t)NB + 1) * 4);
  int* row_off = (int*)alloc(((size_t)NN + 1) * 4);
  float* h    = (float*)alloc((size_t)NN * 32 * 4);
  __half* a   = (__half*)alloc((size_t)NN * 32 * 2);
  float* bp   = (float*)alloc((size_t)NN * 32 * 4);
  float* agg  = (float*)alloc((size_t)NN * 32 * 4);
  float2* Vp  = (float2*)alloc((size_t)NN * 8);

  k_hist<<<NCH, 1024, 0, stream>>>(recv, histmat);
  k_scanA<<<(NB + 255) / 256, 256, 0, stream>>>(histmat, total);
  k_scanB<<<1, 256, 0, stream>>>(total, boff);
  k_scanC<<<(NB + 255) / 256, 256, 0, stream>>>(histmat, boff);
  k_scat<<<NCH, 1024, 0, stream>>>(send, recv, (const float2*)ef, mask, histmat, sorted);
  k_bsort<<<NB, 256, 0, stream>>>(boff, sorted, row_off);

  k_init<<<NBLK, 256, 0, stream>>>((const float2*)PQ, Win, bin, Wmsg, bmsg, h, a, bp, Vp);

  for (int l = 0; l < 3; l++) {
    int last = (l == 2) ? 1 : 0;
    int lnext = (l + 1) % 3;
    k_edge<<<EBK2, 128, 0, stream>>>(a, bp, row_off, (const f32x4*)sorted, Wmsg + l * 70 * 32, agg);
    k_node<<<NBLK, 256, 0, stream>>>(agg, Wupd + l * 66 * 32, bupd + l * 32,
                                     Wdel + l * 64, bdel + l * 2,
                                     Wmsg + lnext * 70 * 32, bmsg + lnext * 32,
                                     h, a, bp, Vp, out, last);
  }
}

// Round 18
// 525.082 us; speedup vs baseline: 1.4755x; 1.0622x over previous
//
#include <hip/hip_runtime.h>
#include <hip/hip_fp16.h>

#define NN 100000
#define NE 3200000
#define NB 1563            // ceil(NN/64) buckets of 64 receiver nodes
#define NBLK ((NN + 255) / 256)
#define CHUNK 8192
#define NCH 391            // ceil(NE/CHUNK)
#define CAP 3072           // max edges per 64-node bucket (mean 2048, sigma ~45; +22 sigma)
#define NKEY 4096          // bsort bins: rl(6b) x sender-granule-2048 (6b)
#define EBK2 ((NN + 31) / 32)   // k_edge: 32 nodes/block, 128 threads

typedef float f32x4 __attribute__((ext_vector_type(4)));
typedef unsigned int u32x4 __attribute__((ext_vector_type(4)));

__device__ __forceinline__ float2 h2f2(unsigned int u) {
  __half2 h;
  *reinterpret_cast<unsigned int*>(&h) = u;
  return __half22float2(h);
}
__device__ __forceinline__ unsigned int f2h2(float x, float y) {
  __half2 h = __floats2half2_rn(x, y);
  return *reinterpret_cast<unsigned int*>(&h);
}

// ---------------- pass 1: per-chunk bucket histogram, layout histmat[c*NB + b] ----------------

__global__ __launch_bounds__(1024) void k_hist(const int* __restrict__ recv, int* __restrict__ histmat) {
  __shared__ int h[NB];
  int t = threadIdx.x, c = blockIdx.x;
  for (int i = t; i < NB; i += 1024) h[i] = 0;
  __syncthreads();
  int start = c * CHUNK;
  int end = min(start + CHUNK, NE);
  for (int i = start + t; i < end; i += 1024)
    atomicAdd(&h[__builtin_nontemporal_load(recv + i) >> 6], 1);
  __syncthreads();
  for (int i = t; i < NB; i += 1024) histmat[c * NB + i] = h[i];
}

// ---------------- scan A: per-bucket totals (coalesced over b) ----------------

__global__ __launch_bounds__(256) void k_scanA(const int* __restrict__ histmat, int* __restrict__ total) {
  int b = blockIdx.x * 256 + threadIdx.x;
  if (b >= NB) return;
  int s = 0;
#pragma unroll 4
  for (int c = 0; c < NCH; c++) s += histmat[c * NB + b];
  total[b] = s;
}

// ---------------- scan B: exclusive scan of bucket totals -> boff[b] ----------------

__global__ __launch_bounds__(256) void k_scanB(const int* __restrict__ total, int* __restrict__ boff) {
  __shared__ int ps[256];
  int t = threadIdx.x;
  const int PER = (NB + 255) / 256;  // 7
  int v[PER];
  int s = 0;
#pragma unroll
  for (int k = 0; k < PER; k++) {
    int i = t * PER + k;
    v[k] = (i < NB) ? total[i] : 0;
    s += v[k];
  }
  ps[t] = s;
  __syncthreads();
  for (int o = 1; o < 256; o <<= 1) {
    int x = (t >= o) ? ps[t - o] : 0;
    __syncthreads();
    ps[t] += x;
    __syncthreads();
  }
  int run = (t > 0) ? ps[t - 1] : 0;
#pragma unroll
  for (int k = 0; k < PER; k++) {
    int i = t * PER + k;
    if (i < NB) {
      boff[i] = run;
      run += v[k];
    }
  }
  if (t == 255) boff[NB] = ps[255];
}

// ---------------- scan C: per-bucket running offsets over chunks (coalesced over b) ----------------

__global__ __launch_bounds__(256) void k_scanC(int* __restrict__ histmat, const int* __restrict__ boff) {
  int b = blockIdx.x * 256 + threadIdx.x;
  if (b >= NB) return;
  int run = boff[b];
#pragma unroll 4
  for (int c = 0; c < NCH; c++) {
    int v = histmat[c * NB + b];
    histmat[c * NB + b] = run;
    run += v;
  }
}

// ---------------- pass 2: scatter; coalesced reads AND writes via full LDS record staging ----------

__global__ __launch_bounds__(1024) void k_scat(const int* __restrict__ send, const int* __restrict__ recv,
                                               const float2* __restrict__ ef, const float* __restrict__ mask,
                                               const int* __restrict__ boffc, float4* __restrict__ sorted) {
  __shared__ float4 stg[CHUNK];            // 128 KB
  __shared__ unsigned short bkt[CHUNK];    // 16 KB
  __shared__ int ofs[NB];                  // 6.25 KB
  __shared__ int cur[NB];                  // 6.25 KB
  __shared__ int wsum[16];
  int t = threadIdx.x, c = blockIdx.x;
  int start = c * CHUNK;
  int end = min(start + CHUNK, NE);
  int len = end - start;
  for (int i = t; i < NB; i += 1024) cur[i] = 0;
  __syncthreads();
  for (int i = start + t; i < end; i += 1024)
    atomicAdd(&cur[__builtin_nontemporal_load(recv + i) >> 6], 1);
  __syncthreads();
  int v0 = (2 * t < NB) ? cur[2 * t] : 0;
  int v1 = (2 * t + 1 < NB) ? cur[2 * t + 1] : 0;
  int s = v0 + v1;
  int lane = t & 63, wid = t >> 6;
  for (int o = 1; o < 64; o <<= 1) {
    int x = __shfl_up(s, o);
    if (lane >= o) s += x;
  }
  if (lane == 63) wsum[wid] = s;
  __syncthreads();
  if (wid == 0) {
    int ws = (lane < 16) ? wsum[lane] : 0;
    for (int o = 1; o < 16; o <<= 1) {
      int x = __shfl_up(ws, o);
      if (lane >= o) ws += x;
    }
    if (lane < 16) wsum[lane] = ws;
  }
  __syncthreads();
  int excl = s - v0 - v1 + ((wid > 0) ? wsum[wid - 1] : 0);
  __syncthreads();
  if (2 * t < NB) {
    cur[2 * t] = excl;
    ofs[2 * t] = boffc[c * NB + 2 * t] - excl;
  }
  if (2 * t + 1 < NB) {
    cur[2 * t + 1] = excl + v0;
    ofs[2 * t + 1] = boffc[c * NB + 2 * t + 1] - (excl + v0);
  }
  __syncthreads();
  for (int i = start + t; i < end; i += 1024) {
    int r = recv[i];
    int b = r >> 6;
    int p = atomicAdd(&cur[b], 1);
    float2 e2 = ef[i];
    float4 vv;
    vv.x = __int_as_float((send[i] << 6) | (r & 63));  // 17b sender | 6b local receiver
    vv.y = e2.x;
    vv.z = e2.y;
    vv.w = mask[i];
    stg[p] = vv;
    bkt[p] = (unsigned short)b;
  }
  __syncthreads();
  for (int p = t; p < len; p += 1024) {
    int b = bkt[p];
    sorted[ofs[b] + p] = stg[p];
  }
}

// ---------------- per-bucket counting sort by key=(rl, sender>>11) + row_off ----------------
// 4096 bins, 512 thr, CAP 3072 -> 66 KB LDS -> 2 blocks/CU.

__global__ __launch_bounds__(512) void k_bsort(const int* __restrict__ boff, float4* __restrict__ sorted,
                                               int* __restrict__ row_off) {
  __shared__ int cnt[NKEY];   // 16 KB
  __shared__ int part[512];   // 2 KB
  __shared__ float4 stg[CAP]; // 48 KB
  int t = threadIdx.x, b = blockIdx.x;
  int base = boff[b], end = boff[b + 1];
  int Eb = end - base;
  int n0 = b * 64;
  for (int i = t; i < NKEY; i += 512) cnt[i] = 0;
  __syncthreads();
  for (int e = base + t; e < end; e += 512) {
    int pk = __float_as_int(sorted[e].x);
    int key = ((pk & 63) << 6) | (pk >> 17);  // rl major, 2048-node sender granule minor
    atomicAdd(&cnt[key], 1);
  }
  __syncthreads();
  int s = 0;
#pragma unroll
  for (int k = 0; k < 8; k++) s += cnt[t * 8 + k];
  part[t] = s;
  __syncthreads();
  for (int o = 1; o < 512; o <<= 1) {
    int x = (t >= o) ? part[t - o] : 0;
    __syncthreads();
    part[t] += x;
    __syncthreads();
  }
  int run = part[t] - s;
#pragma unroll
  for (int k = 0; k < 8; k++) {
    int c = cnt[t * 8 + k];
    cnt[t * 8 + k] = run;
    run += c;
  }
  __syncthreads();
  if (t < 64) {
    int n = n0 + t;
    if (n < NN) row_off[n] = base + cnt[t << 6];
  }
  if (b == NB - 1 && t == 0) row_off[NN] = end;
  __syncthreads();
  for (int e = base + t; e < end; e += 512) {
    float4 r = sorted[e];
    int pk = __float_as_int(r.x);
    int key = ((pk & 63) << 6) | (pk >> 17);
    int p = atomicAdd(&cnt[key], 1);
    stg[p] = r;
  }
  __syncthreads();
  for (int i = t; i < Eb; i += 512) sorted[base + i] = stg[i];
}

// ---------------- init: h = PQ@W_in + b_in ; Vp=(1,0); layer-0 a,b projections ----------------
// a stored fp16 node-major: a[n*32 + ch] -> one 64B line per node.

__global__ __launch_bounds__(256) void k_init(const float2* __restrict__ PQ,
                                              const float* __restrict__ Win, const float* __restrict__ bin,
                                              const float* __restrict__ Wm, const float* __restrict__ bm,
                                              float* __restrict__ h, __half* __restrict__ a,
                                              float* __restrict__ bp, float2* __restrict__ Vp) {
  int n = blockIdx.x * 256 + threadIdx.x;
  if (n >= NN) return;
  float2 pq = PQ[n];
  float hh[32];
#pragma unroll
  for (int j = 0; j < 32; j++) hh[j] = fmaf(pq.x, Win[j], fmaf(pq.y, Win[32 + j], bin[j]));
  float4* h4 = (float4*)(h + (size_t)n * 32);
#pragma unroll
  for (int j = 0; j < 8; j++) h4[j] = make_float4(hh[4*j], hh[4*j+1], hh[4*j+2], hh[4*j+3]);
  Vp[n] = make_float2(1.0f, 0.0f);
  float av[32], bv[32];
#pragma unroll
  for (int j = 0; j < 32; j++) { av[j] = Wm[j]; bv[j] = Wm[34 * 32 + j] + bm[j]; }
#pragma unroll 1
  for (int k = 0; k < 32; k++) {
    float hk = hh[k];
#pragma unroll
    for (int j = 0; j < 32; j++) {
      av[j] = fmaf(hk, Wm[(2 + k) * 32 + j], av[j]);
      bv[j] = fmaf(hk, Wm[(36 + k) * 32 + j], bv[j]);
    }
  }
  u32x4* dst = (u32x4*)(a + (size_t)n * 32);
#pragma unroll
  for (int g = 0; g < 4; g++) {
    u32x4 p;
    p.x = f2h2(av[g*8+0], av[g*8+1]);
    p.y = f2h2(av[g*8+2], av[g*8+3]);
    p.z = f2h2(av[g*8+4], av[g*8+5]);
    p.w = f2h2(av[g*8+6], av[g*8+7]);
    dst[g] = p;
  }
  float4* b4 = (float4*)(bp + (size_t)n * 32);
#pragma unroll
  for (int j = 0; j < 8; j++) b4[j] = make_float4(bv[4*j], bv[4*j+1], bv[4*j+2], bv[4*j+3]);
}

// ---------------- per-layer edge aggregation: 4 lanes/node + 2-deep gather pipeline ----------------

__global__ __launch_bounds__(128) void k_edge(const __half* __restrict__ a, const float* __restrict__ bp,
                                              const int* __restrict__ row_off, const f32x4* __restrict__ sorted,
                                              const float* __restrict__ Wm, float* __restrict__ agg) {
  int t = threadIdx.x;
  int n = blockIdx.x * 32 + (t >> 2);
  if (n >= NN) return;
  int ch = (t & 3) * 8;
  const float* wr = Wm + 68 * 32 + ch;
  float w0[8], w1[8];
#pragma unroll
  for (int j = 0; j < 8; j++) { w0[j] = wr[j]; w1[j] = wr[32 + j]; }
  const float4 bna = *(const float4*)(bp + (size_t)n * 32 + ch);
  const float4 bnb = *(const float4*)(bp + (size_t)n * 32 + ch + 4);
  float bn[8] = {bna.x, bna.y, bna.z, bna.w, bnb.x, bnb.y, bnb.z, bnb.w};
  float acc[8] = {0.f, 0.f, 0.f, 0.f, 0.f, 0.f, 0.f, 0.f};
  const __half* abase = a + ch;
  int e0 = row_off[n], e1 = row_off[n + 1];
  f32x4 r0 = {0,0,0,0}, r1 = {0,0,0,0}, r2 = {0,0,0,0};
  u32x4 gA = {0,0,0,0}, gB = {0,0,0,0};
  if (e0 < e1)     r0 = __builtin_nontemporal_load(sorted + e0);
  if (e0 + 1 < e1) r1 = __builtin_nontemporal_load(sorted + e0 + 1);
  if (e0 + 2 < e1) r2 = __builtin_nontemporal_load(sorted + e0 + 2);
  if (e0 < e1)     gA = *(const u32x4*)(abase + (size_t)(__float_as_int(r0.x) >> 6) * 32);
  if (e0 + 1 < e1) gB = *(const u32x4*)(abase + (size_t)(__float_as_int(r1.x) >> 6) * 32);
  for (int e = e0; e < e1; ++e) {
    f32x4 rc = r0;
    u32x4 q = gA;
    r0 = r1; r1 = r2; gA = gB;
    if (e + 3 < e1) r2 = __builtin_nontemporal_load(sorted + e + 3);   // record 3 ahead
    if (e + 2 < e1)                                                    // gather 2 ahead (r1 = rec e+2)
      gB = *(const u32x4*)(abase + (size_t)(__float_as_int(r1.x) >> 6) * 32);
    float c0 = rc.y, c1 = rc.z, mk = rc.w;
    float2 f0 = h2f2(q.x), f1 = h2f2(q.y), f2 = h2f2(q.z), f3 = h2f2(q.w);
    float av[8] = {f0.x, f0.y, f1.x, f1.y, f2.x, f2.y, f3.x, f3.y};
#pragma unroll
    for (int j = 0; j < 8; j++)
      acc[j] = fmaf(fmaxf(av[j] + fmaf(c0, w0[j], fmaf(c1, w1[j], bn[j])), 0.f), mk, acc[j]);
  }
  float* gp = agg + (size_t)n * 32 + ch;
  *(float4*)gp       = make_float4(acc[0], acc[1], acc[2], acc[3]);
  *(float4*)(gp + 4) = make_float4(acc[4], acc[5], acc[6], acc[7]);
}

// ---------------- per-layer node update (+ next-layer projections fused) ----------------

__global__ __launch_bounds__(256) void k_node(const float* __restrict__ agg,
                                              const float* __restrict__ Wu, const float* __restrict__ bu,
                                              const float* __restrict__ Wd, const float* __restrict__ bd,
                                              const float* __restrict__ Wm, const float* __restrict__ bm,
                                              float* __restrict__ h, __half* __restrict__ a,
                                              float* __restrict__ bp, float2* __restrict__ Vp,
                                              float2* __restrict__ out, int last) {
  int n = blockIdx.x * 256 + threadIdx.x;
  if (n >= NN) return;
  float2 vp = Vp[n];
  float v0 = vp.x, v1 = vp.y;
  float hh[32], ag[32];
  const float4* h4 = (const float4*)(h + (size_t)n * 32);
  const float4* g4 = (const float4*)(agg + (size_t)n * 32);
#pragma unroll
  for (int jj = 0; jj < 8; jj++) {
    float4 x = h4[jj];
    hh[4*jj] = x.x; hh[4*jj+1] = x.y; hh[4*jj+2] = x.z; hh[4*jj+3] = x.w;
    float4 y = g4[jj];
    ag[4*jj] = y.x; ag[4*jj+1] = y.y; ag[4*jj+2] = y.z; ag[4*jj+3] = y.w;
  }
  float vo[32];
#pragma unroll
  for (int j = 0; j < 32; j++) vo[j] = fmaf(v0, Wu[j], fmaf(v1, Wu[32 + j], bu[j]));
#pragma unroll 1
  for (int k = 0; k < 32; k++) {
    float hk = hh[k], ak = ag[k];
#pragma unroll
    for (int j = 0; j < 32; j++) {
      vo[j] = fmaf(hk, Wu[(2 + k) * 32 + j], vo[j]);
      vo[j] = fmaf(ak, Wu[(34 + k) * 32 + j], vo[j]);
    }
  }
#pragma unroll
  for (int j = 0; j < 32; j++) hh[j] = fmaxf(vo[j], 0.0f);
  float d0 = bd[0], d1 = bd[1];
#pragma unroll 1
  for (int k = 0; k < 32; k++) {
    d0 = fmaf(hh[k], Wd[2 * k], d0);
    d1 = fmaf(hh[k], Wd[2 * k + 1], d1);
  }
  v0 += d0;
  v1 += d1;
  if (last) {
    out[n] = make_float2(v0, v1);
    return;
  }
  Vp[n] = make_float2(v0, v1);
  float4* hw4 = (float4*)(h + (size_t)n * 32);
#pragma unroll
  for (int jj = 0; jj < 8; jj++) hw4[jj] = make_float4(hh[4*jj], hh[4*jj+1], hh[4*jj+2], hh[4*jj+3]);
  float av[32], bv[32];
#pragma unroll
  for (int j = 0; j < 32; j++) {
    av[j] = fmaf(v0, Wm[j], v1 * Wm[32 + j]);
    bv[j] = fmaf(v0, Wm[34 * 32 + j], fmaf(v1, Wm[35 * 32 + j], bm[j]));
  }
#pragma unroll 1
  for (int k = 0; k < 32; k++) {
    float hk = hh[k];
#pragma unroll
    for (int j = 0; j < 32; j++) {
      av[j] = fmaf(hk, Wm[(2 + k) * 32 + j], av[j]);
      bv[j] = fmaf(hk, Wm[(36 + k) * 32 + j], bv[j]);
    }
  }
  u32x4* dst = (u32x4*)(a + (size_t)n * 32);
#pragma unroll
  for (int g = 0; g < 4; g++) {
    u32x4 p;
    p.x = f2h2(av[g*8+0], av[g*8+1]);
    p.y = f2h2(av[g*8+2], av[g*8+3]);
    p.z = f2h2(av[g*8+4], av[g*8+5]);
    p.w = f2h2(av[g*8+6], av[g*8+7]);
    dst[g] = p;
  }
  float4* b4 = (float4*)(bp + (size_t)n * 32);
#pragma unroll
  for (int jj = 0; jj < 8; jj++) b4[jj] = make_float4(bv[4*jj], bv[4*jj+1], bv[4*jj+2], bv[4*jj+3]);
}

// ---------------- launch ----------------

extern "C" void kernel_launch(void* const* d_in, const int* in_sizes, int n_in,
                              void* d_out, int out_size, void* d_ws, size_t ws_size,
                              hipStream_t stream) {
  const float* PQ   = (const float*)d_in[0];
  const int*   send = (const int*)d_in[1];
  const int*   recv = (const int*)d_in[2];
  const float* ef   = (const float*)d_in[3];
  const float* mask = (const float*)d_in[4];
  const float* Win  = (const float*)d_in[5];
  const float* bin  = (const float*)d_in[6];
  const float* Wmsg = (const float*)d_in[7];   // [3,70,32]
  const float* bmsg = (const float*)d_in[8];   // [3,32]
  const float* Wupd = (const float*)d_in[9];   // [3,66,32]
  const float* bupd = (const float*)d_in[10];  // [3,32]
  const float* Wdel = (const float*)d_in[11];  // [3,32,2]
  const float* bdel = (const float*)d_in[12];  // [3,2]
  float2* out = (float2*)d_out;

  char* w = (char*)d_ws;
  auto alloc = [&](size_t bytes) {
    char* p = w;
    w += (bytes + 255) & ~(size_t)255;
    return p;
  };
  float4* sorted = (float4*)alloc((size_t)NE * 16);
  int* histmat = (int*)alloc((size_t)NCH * NB * 4);  // [c][b]; in-place -> per-chunk offsets
  int* total   = (int*)alloc((size_t)NB * 4);
  int* boff    = (int*)alloc(((size_t)NB + 1) * 4);
  int* row_off = (int*)alloc(((size_t)NN + 1) * 4);
  float* h    = (float*)alloc((size_t)NN * 32 * 4);
  __half* a   = (__half*)alloc((size_t)NN * 32 * 2);
  float* bp   = (float*)alloc((size_t)NN * 32 * 4);
  float* agg  = (float*)alloc((size_t)NN * 32 * 4);
  float2* Vp  = (float2*)alloc((size_t)NN * 8);

  k_hist<<<NCH, 1024, 0, stream>>>(recv, histmat);
  k_scanA<<<(NB + 255) / 256, 256, 0, stream>>>(histmat, total);
  k_scanB<<<1, 256, 0, stream>>>(total, boff);
  k_scanC<<<(NB + 255) / 256, 256, 0, stream>>>(histmat, boff);
  k_scat<<<NCH, 1024, 0, stream>>>(send, recv, (const float2*)ef, mask, histmat, sorted);
  k_bsort<<<NB, 512, 0, stream>>>(boff, sorted, row_off);

  k_init<<<NBLK, 256, 0, stream>>>((const float2*)PQ, Win, bin, Wmsg, bmsg, h, a, bp, Vp);

  for (int l = 0; l < 3; l++) {
    int last = (l == 2) ? 1 : 0;
    int lnext = (l + 1) % 3;
    k_edge<<<EBK2, 128, 0, stream>>>(a, bp, row_off, (const f32x4*)sorted, Wmsg + l * 70 * 32, agg);
    k_node<<<NBLK, 256, 0, stream>>>(agg, Wupd + l * 66 * 32, bupd + l * 32,
                                     Wdel + l * 64, bdel + l * 2,
                                     Wmsg + lnext * 70 * 32, bmsg + lnext * 32,
                                     h, a, bp, Vp, out, last);
  }
}

// Round 19
// 524.959 us; speedup vs baseline: 1.4759x; 1.0002x over previous
//
#include <hip/hip_runtime.h>
#include <hip/hip_fp16.h>

#define NN 100000
#define NE 3200000
#define NB 1563            // ceil(NN/64) buckets of 64 receiver nodes
#define NBLK ((NN + 255) / 256)
#define CHUNK 8192
#define NCH 391            // ceil(NE/CHUNK)
#define CAP 3072           // max edges per 64-node bucket (mean 2048, sigma ~45; +22 sigma)
#define NKEY 4096          // bsort bins: rl(6b) x sender-granule-2048 (6b)
#define EBK2 ((NN + 31) / 32)   // k_edge: 32 nodes/block, 128 threads

typedef float f32x4 __attribute__((ext_vector_type(4)));
typedef unsigned int u32x4 __attribute__((ext_vector_type(4)));

__device__ __forceinline__ float2 h2f2(unsigned int u) {
  __half2 h;
  *reinterpret_cast<unsigned int*>(&h) = u;
  return __half22float2(h);
}
__device__ __forceinline__ unsigned int f2h2(float x, float y) {
  __half2 h = __floats2half2_rn(x, y);
  return *reinterpret_cast<unsigned int*>(&h);
}

// ---------------- pass 1: per-chunk bucket histogram, layout histmat[c*NB + b] ----------------

__global__ __launch_bounds__(1024) void k_hist(const int* __restrict__ recv, int* __restrict__ histmat) {
  __shared__ int h[NB];
  int t = threadIdx.x, c = blockIdx.x;
  for (int i = t; i < NB; i += 1024) h[i] = 0;
  __syncthreads();
  int start = c * CHUNK;
  int end = min(start + CHUNK, NE);
  for (int i = start + t; i < end; i += 1024)
    atomicAdd(&h[__builtin_nontemporal_load(recv + i) >> 6], 1);
  __syncthreads();
  for (int i = t; i < NB; i += 1024) histmat[c * NB + i] = h[i];
}

// ---------------- scan A: per-bucket totals (coalesced over b) ----------------

__global__ __launch_bounds__(256) void k_scanA(const int* __restrict__ histmat, int* __restrict__ total) {
  int b = blockIdx.x * 256 + threadIdx.x;
  if (b >= NB) return;
  int s = 0;
#pragma unroll 4
  for (int c = 0; c < NCH; c++) s += histmat[c * NB + b];
  total[b] = s;
}

// ---------------- scan B: exclusive scan of bucket totals -> boff[b] ----------------

__global__ __launch_bounds__(256) void k_scanB(const int* __restrict__ total, int* __restrict__ boff) {
  __shared__ int ps[256];
  int t = threadIdx.x;
  const int PER = (NB + 255) / 256;  // 7
  int v[PER];
  int s = 0;
#pragma unroll
  for (int k = 0; k < PER; k++) {
    int i = t * PER + k;
    v[k] = (i < NB) ? total[i] : 0;
    s += v[k];
  }
  ps[t] = s;
  __syncthreads();
  for (int o = 1; o < 256; o <<= 1) {
    int x = (t >= o) ? ps[t - o] : 0;
    __syncthreads();
    ps[t] += x;
    __syncthreads();
  }
  int run = (t > 0) ? ps[t - 1] : 0;
#pragma unroll
  for (int k = 0; k < PER; k++) {
    int i = t * PER + k;
    if (i < NB) {
      boff[i] = run;
      run += v[k];
    }
  }
  if (t == 255) boff[NB] = ps[255];
}

// ---------------- scan C: per-bucket running offsets over chunks (coalesced over b) ----------------

__global__ __launch_bounds__(256) void k_scanC(int* __restrict__ histmat, const int* __restrict__ boff) {
  int b = blockIdx.x * 256 + threadIdx.x;
  if (b >= NB) return;
  int run = boff[b];
#pragma unroll 4
  for (int c = 0; c < NCH; c++) {
    int v = histmat[c * NB + b];
    histmat[c * NB + b] = run;
    run += v;
  }
}

// ---------------- pass 2: scatter; coalesced reads AND writes via full LDS record staging ----------

__global__ __launch_bounds__(1024) void k_scat(const int* __restrict__ send, const int* __restrict__ recv,
                                               const float2* __restrict__ ef, const float* __restrict__ mask,
                                               const int* __restrict__ boffc, float4* __restrict__ sorted) {
  __shared__ float4 stg[CHUNK];            // 128 KB
  __shared__ unsigned short bkt[CHUNK];    // 16 KB
  __shared__ int ofs[NB];                  // 6.25 KB
  __shared__ int cur[NB];                  // 6.25 KB
  __shared__ int wsum[16];
  int t = threadIdx.x, c = blockIdx.x;
  int start = c * CHUNK;
  int end = min(start + CHUNK, NE);
  int len = end - start;
  for (int i = t; i < NB; i += 1024) cur[i] = 0;
  __syncthreads();
  for (int i = start + t; i < end; i += 1024)
    atomicAdd(&cur[__builtin_nontemporal_load(recv + i) >> 6], 1);
  __syncthreads();
  int v0 = (2 * t < NB) ? cur[2 * t] : 0;
  int v1 = (2 * t + 1 < NB) ? cur[2 * t + 1] : 0;
  int s = v0 + v1;
  int lane = t & 63, wid = t >> 6;
  for (int o = 1; o < 64; o <<= 1) {
    int x = __shfl_up(s, o);
    if (lane >= o) s += x;
  }
  if (lane == 63) wsum[wid] = s;
  __syncthreads();
  if (wid == 0) {
    int ws = (lane < 16) ? wsum[lane] : 0;
    for (int o = 1; o < 16; o <<= 1) {
      int x = __shfl_up(ws, o);
      if (lane >= o) ws += x;
    }
    if (lane < 16) wsum[lane] = ws;
  }
  __syncthreads();
  int excl = s - v0 - v1 + ((wid > 0) ? wsum[wid - 1] : 0);
  __syncthreads();
  if (2 * t < NB) {
    cur[2 * t] = excl;
    ofs[2 * t] = boffc[c * NB + 2 * t] - excl;
  }
  if (2 * t + 1 < NB) {
    cur[2 * t + 1] = excl + v0;
    ofs[2 * t + 1] = boffc[c * NB + 2 * t + 1] - (excl + v0);
  }
  __syncthreads();
  for (int i = start + t; i < end; i += 1024) {
    int r = recv[i];
    int b = r >> 6;
    int p = atomicAdd(&cur[b], 1);
    float2 e2 = ef[i];
    float4 vv;
    vv.x = __int_as_float((send[i] << 6) | (r & 63));  // 17b sender | 6b local receiver
    vv.y = e2.x;
    vv.z = e2.y;
    vv.w = mask[i];
    stg[p] = vv;
    bkt[p] = (unsigned short)b;
  }
  __syncthreads();
  for (int p = t; p < len; p += 1024) {
    int b = bkt[p];
    sorted[ofs[b] + p] = stg[p];
  }
}

// ---------------- per-bucket counting sort by key=(rl, sender>>11) + row_off ----------------
// 4096 bins, 512 thr, CAP 3072 -> 66 KB LDS -> 2 blocks/CU.

__global__ __launch_bounds__(512) void k_bsort(const int* __restrict__ boff, float4* __restrict__ sorted,
                                               int* __restrict__ row_off) {
  __shared__ int cnt[NKEY];   // 16 KB
  __shared__ int part[512];   // 2 KB
  __shared__ float4 stg[CAP]; // 48 KB
  int t = threadIdx.x, b = blockIdx.x;
  int base = boff[b], end = boff[b + 1];
  int Eb = end - base;
  int n0 = b * 64;
  for (int i = t; i < NKEY; i += 512) cnt[i] = 0;
  __syncthreads();
  for (int e = base + t; e < end; e += 512) {
    int pk = __float_as_int(sorted[e].x);
    int key = ((pk & 63) << 6) | (pk >> 17);  // rl major, 2048-node sender granule minor
    atomicAdd(&cnt[key], 1);
  }
  __syncthreads();
  int s = 0;
#pragma unroll
  for (int k = 0; k < 8; k++) s += cnt[t * 8 + k];
  part[t] = s;
  __syncthreads();
  for (int o = 1; o < 512; o <<= 1) {
    int x = (t >= o) ? part[t - o] : 0;
    __syncthreads();
    part[t] += x;
    __syncthreads();
  }
  int run = part[t] - s;
#pragma unroll
  for (int k = 0; k < 8; k++) {
    int c = cnt[t * 8 + k];
    cnt[t * 8 + k] = run;
    run += c;
  }
  __syncthreads();
  if (t < 64) {
    int n = n0 + t;
    if (n < NN) row_off[n] = base + cnt[t << 6];
  }
  if (b == NB - 1 && t == 0) row_off[NN] = end;
  __syncthreads();
  for (int e = base + t; e < end; e += 512) {
    float4 r = sorted[e];
    int pk = __float_as_int(r.x);
    int key = ((pk & 63) << 6) | (pk >> 17);
    int p = atomicAdd(&cnt[key], 1);
    stg[p] = r;
  }
  __syncthreads();
  for (int i = t; i < Eb; i += 512) sorted[base + i] = stg[i];
}

// ---------------- init: h = PQ@W_in + b_in ; Vp=(1,0); layer-0 a,b projections ----------------
// a stored fp16 node-major: a[n*32 + ch] -> one 64B line per node.

__global__ __launch_bounds__(256) void k_init(const float2* __restrict__ PQ,
                                              const float* __restrict__ Win, const float* __restrict__ bin,
                                              const float* __restrict__ Wm, const float* __restrict__ bm,
                                              float* __restrict__ h, __half* __restrict__ a,
                                              float* __restrict__ bp, float2* __restrict__ Vp) {
  int n = blockIdx.x * 256 + threadIdx.x;
  if (n >= NN) return;
  float2 pq = PQ[n];
  float hh[32];
#pragma unroll
  for (int j = 0; j < 32; j++) hh[j] = fmaf(pq.x, Win[j], fmaf(pq.y, Win[32 + j], bin[j]));
  float4* h4 = (float4*)(h + (size_t)n * 32);
#pragma unroll
  for (int j = 0; j < 8; j++) h4[j] = make_float4(hh[4*j], hh[4*j+1], hh[4*j+2], hh[4*j+3]);
  Vp[n] = make_float2(1.0f, 0.0f);
  float av[32], bv[32];
#pragma unroll
  for (int j = 0; j < 32; j++) { av[j] = Wm[j]; bv[j] = Wm[34 * 32 + j] + bm[j]; }
#pragma unroll 1
  for (int k = 0; k < 32; k++) {
    float hk = hh[k];
#pragma unroll
    for (int j = 0; j < 32; j++) {
      av[j] = fmaf(hk, Wm[(2 + k) * 32 + j], av[j]);
      bv[j] = fmaf(hk, Wm[(36 + k) * 32 + j], bv[j]);
    }
  }
  u32x4* dst = (u32x4*)(a + (size_t)n * 32);
#pragma unroll
  for (int g = 0; g < 4; g++) {
    u32x4 p;
    p.x = f2h2(av[g*8+0], av[g*8+1]);
    p.y = f2h2(av[g*8+2], av[g*8+3]);
    p.z = f2h2(av[g*8+4], av[g*8+5]);
    p.w = f2h2(av[g*8+6], av[g*8+7]);
    dst[g] = p;
  }
  float4* b4 = (float4*)(bp + (size_t)n * 32);
#pragma unroll
  for (int j = 0; j < 8; j++) b4[j] = make_float4(bv[4*j], bv[4*j+1], bv[4*j+2], bv[4*j+3]);
}

// ---------------- per-layer edge aggregation: 4 lanes/node + 3-deep gather pipeline ----------------

__global__ __launch_bounds__(128) void k_edge(const __half* __restrict__ a, const float* __restrict__ bp,
                                              const int* __restrict__ row_off, const f32x4* __restrict__ sorted,
                                              const float* __restrict__ Wm, float* __restrict__ agg) {
  int t = threadIdx.x;
  int n = blockIdx.x * 32 + (t >> 2);
  if (n >= NN) return;
  int ch = (t & 3) * 8;
  const float* wr = Wm + 68 * 32 + ch;
  float w0[8], w1[8];
#pragma unroll
  for (int j = 0; j < 8; j++) { w0[j] = wr[j]; w1[j] = wr[32 + j]; }
  const float4 bna = *(const float4*)(bp + (size_t)n * 32 + ch);
  const float4 bnb = *(const float4*)(bp + (size_t)n * 32 + ch + 4);
  float bn[8] = {bna.x, bna.y, bna.z, bna.w, bnb.x, bnb.y, bnb.z, bnb.w};
  float acc[8] = {0.f, 0.f, 0.f, 0.f, 0.f, 0.f, 0.f, 0.f};
  const __half* abase = a + ch;
  int e0 = row_off[n], e1 = row_off[n + 1];
  f32x4 r0 = {0,0,0,0}, r1 = {0,0,0,0}, r2 = {0,0,0,0}, r3 = {0,0,0,0};
  u32x4 gA = {0,0,0,0}, gB = {0,0,0,0}, gC = {0,0,0,0};
  if (e0 < e1)     r0 = __builtin_nontemporal_load(sorted + e0);
  if (e0 + 1 < e1) r1 = __builtin_nontemporal_load(sorted + e0 + 1);
  if (e0 + 2 < e1) r2 = __builtin_nontemporal_load(sorted + e0 + 2);
  if (e0 + 3 < e1) r3 = __builtin_nontemporal_load(sorted + e0 + 3);
  if (e0 < e1)     gA = *(const u32x4*)(abase + (size_t)(__float_as_int(r0.x) >> 6) * 32);
  if (e0 + 1 < e1) gB = *(const u32x4*)(abase + (size_t)(__float_as_int(r1.x) >> 6) * 32);
  if (e0 + 2 < e1) gC = *(const u32x4*)(abase + (size_t)(__float_as_int(r2.x) >> 6) * 32);
  for (int e = e0; e < e1; ++e) {
    f32x4 rc = r0;
    u32x4 q = gA;
    r0 = r1; r1 = r2; r2 = r3;
    gA = gB; gB = gC;
    if (e + 4 < e1) r3 = __builtin_nontemporal_load(sorted + e + 4);   // record 4 ahead
    if (e + 3 < e1)                                                    // gather 3 ahead (r2 = rec e+3)
      gC = *(const u32x4*)(abase + (size_t)(__float_as_int(r2.x) >> 6) * 32);
    float c0 = rc.y, c1 = rc.z, mk = rc.w;
    float2 f0 = h2f2(q.x), f1 = h2f2(q.y), f2 = h2f2(q.z), f3 = h2f2(q.w);
    float av[8] = {f0.x, f0.y, f1.x, f1.y, f2.x, f2.y, f3.x, f3.y};
#pragma unroll
    for (int j = 0; j < 8; j++)
      acc[j] = fmaf(fmaxf(av[j] + fmaf(c0, w0[j], fmaf(c1, w1[j], bn[j])), 0.f), mk, acc[j]);
  }
  float* gp = agg + (size_t)n * 32 + ch;
  *(float4*)gp       = make_float4(acc[0], acc[1], acc[2], acc[3]);
  *(float4*)(gp + 4) = make_float4(acc[4], acc[5], acc[6], acc[7]);
}

// ---------------- per-layer node update (+ next-layer projections fused) ----------------

__global__ __launch_bounds__(256) void k_node(const float* __restrict__ agg,
                                              const float* __restrict__ Wu, const float* __restrict__ bu,
                                              const float* __restrict__ Wd, const float* __restrict__ bd,
                                              const float* __restrict__ Wm, const float* __restrict__ bm,
                                              float* __restrict__ h, __half* __restrict__ a,
                                              float* __restrict__ bp, float2* __restrict__ Vp,
                                              float2* __restrict__ out, int last) {
  int n = blockIdx.x * 256 + threadIdx.x;
  if (n >= NN) return;
  float2 vp = Vp[n];
  float v0 = vp.x, v1 = vp.y;
  float hh[32], ag[32];
  const float4* h4 = (const float4*)(h + (size_t)n * 32);
  const float4* g4 = (const float4*)(agg + (size_t)n * 32);
#pragma unroll
  for (int jj = 0; jj < 8; jj++) {
    float4 x = h4[jj];
    hh[4*jj] = x.x; hh[4*jj+1] = x.y; hh[4*jj+2] = x.z; hh[4*jj+3] = x.w;
    float4 y = g4[jj];
    ag[4*jj] = y.x; ag[4*jj+1] = y.y; ag[4*jj+2] = y.z; ag[4*jj+3] = y.w;
  }
  float vo[32];
#pragma unroll
  for (int j = 0; j < 32; j++) vo[j] = fmaf(v0, Wu[j], fmaf(v1, Wu[32 + j], bu[j]));
#pragma unroll 1
  for (int k = 0; k < 32; k++) {
    float hk = hh[k], ak = ag[k];
#pragma unroll
    for (int j = 0; j < 32; j++) {
      vo[j] = fmaf(hk, Wu[(2 + k) * 32 + j], vo[j]);
      vo[j] = fmaf(ak, Wu[(34 + k) * 32 + j], vo[j]);
    }
  }
#pragma unroll
  for (int j = 0; j < 32; j++) hh[j] = fmaxf(vo[j], 0.0f);
  float d0 = bd[0], d1 = bd[1];
#pragma unroll 1
  for (int k = 0; k < 32; k++) {
    d0 = fmaf(hh[k], Wd[2 * k], d0);
    d1 = fmaf(hh[k], Wd[2 * k + 1], d1);
  }
  v0 += d0;
  v1 += d1;
  if (last) {
    out[n] = make_float2(v0, v1);
    return;
  }
  Vp[n] = make_float2(v0, v1);
  float4* hw4 = (float4*)(h + (size_t)n * 32);
#pragma unroll
  for (int jj = 0; jj < 8; jj++) hw4[jj] = make_float4(hh[4*jj], hh[4*jj+1], hh[4*jj+2], hh[4*jj+3]);
  float av[32], bv[32];
#pragma unroll
  for (int j = 0; j < 32; j++) {
    av[j] = fmaf(v0, Wm[j], v1 * Wm[32 + j]);
    bv[j] = fmaf(v0, Wm[34 * 32 + j], fmaf(v1, Wm[35 * 32 + j], bm[j]));
  }
#pragma unroll 1
  for (int k = 0; k < 32; k++) {
    float hk = hh[k];
#pragma unroll
    for (int j = 0; j < 32; j++) {
      av[j] = fmaf(hk, Wm[(2 + k) * 32 + j], av[j]);
      bv[j] = fmaf(hk, Wm[(36 + k) * 32 + j], bv[j]);
    }
  }
  u32x4* dst = (u32x4*)(a + (size_t)n * 32);
#pragma unroll
  for (int g = 0; g < 4; g++) {
    u32x4 p;
    p.x = f2h2(av[g*8+0], av[g*8+1]);
    p.y = f2h2(av[g*8+2], av[g*8+3]);
    p.z = f2h2(av[g*8+4], av[g*8+5]);
    p.w = f2h2(av[g*8+6], av[g*8+7]);
    dst[g] = p;
  }
  float4* b4 = (float4*)(bp + (size_t)n * 32);
#pragma unroll
  for (int jj = 0; jj < 8; jj++) b4[jj] = make_float4(bv[4*jj], bv[4*jj+1], bv[4*jj+2], bv[4*jj+3]);
}

// ---------------- launch ----------------

extern "C" void kernel_launch(void* const* d_in, const int* in_sizes, int n_in,
                              void* d_out, int out_size, void* d_ws, size_t ws_size,
                              hipStream_t stream) {
  const float* PQ   = (const float*)d_in[0];
  const int*   send = (const int*)d_in[1];
  const int*   recv = (const int*)d_in[2];
  const float* ef   = (const float*)d_in[3];
  const float* mask = (const float*)d_in[4];
  const float* Win  = (const float*)d_in[5];
  const float* bin  = (const float*)d_in[6];
  const float* Wmsg = (const float*)d_in[7];   // [3,70,32]
  const float* bmsg = (const float*)d_in[8];   // [3,32]
  const float* Wupd = (const float*)d_in[9];   // [3,66,32]
  const float* bupd = (const float*)d_in[10];  // [3,32]
  const float* Wdel = (const float*)d_in[11];  // [3,32,2]
  const float* bdel = (const float*)d_in[12];  // [3,2]
  float2* out = (float2*)d_out;

  char* w = (char*)d_ws;
  auto alloc = [&](size_t bytes) {
    char* p = w;
    w += (bytes + 255) & ~(size_t)255;
    return p;
  };
  float4* sorted = (float4*)alloc((size_t)NE * 16);
  int* histmat = (int*)alloc((size_t)NCH * NB * 4);  // [c][b]; in-place -> per-chunk offsets
  int* total   = (int*)alloc((size_t)NB * 4);
  int* boff    = (int*)alloc(((size_t)NB + 1) * 4);
  int* row_off = (int*)alloc(((size_t)NN + 1) * 4);
  float* h    = (float*)alloc((size_t)NN * 32 * 4);
  __half* a   = (__half*)alloc((size_t)NN * 32 * 2);
  float* bp   = (float*)alloc((size_t)NN * 32 * 4);
  float* agg  = (float*)alloc((size_t)NN * 32 * 4);
  float2* Vp  = (float2*)alloc((size_t)NN * 8);

  k_hist<<<NCH, 1024, 0, stream>>>(recv, histmat);
  k_scanA<<<(NB + 255) / 256, 256, 0, stream>>>(histmat, total);
  k_scanB<<<1, 256, 0, stream>>>(total, boff);
  k_scanC<<<(NB + 255) / 256, 256, 0, stream>>>(histmat, boff);
  k_scat<<<NCH, 1024, 0, stream>>>(send, recv, (const float2*)ef, mask, histmat, sorted);
  k_bsort<<<NB, 512, 0, stream>>>(boff, sorted, row_off);

  k_init<<<NBLK, 256, 0, stream>>>((const float2*)PQ, Win, bin, Wmsg, bmsg, h, a, bp, Vp);

  for (int l = 0; l < 3; l++) {
    int last = (l == 2) ? 1 : 0;
    int lnext = (l + 1) % 3;
    k_edge<<<EBK2, 128, 0, stream>>>(a, bp, row_off, (const f32x4*)sorted, Wmsg + l * 70 * 32, agg);
    k_node<<<NBLK, 256, 0, stream>>>(agg, Wupd + l * 66 * 32, bupd + l * 32,
                                     Wdel + l * 64, bdel + l * 2,
                                     Wmsg + lnext * 70 * 32, bmsg + lnext * 32,
                                     h, a, bp, Vp, out, last);
  }
}